// Round 3
// baseline (36.693 us; speedup 1.0000x reference)
//
#include <hip/hip_runtime.h>

// CountVectorizer: hash 4x4-byte packed word groups, look up in collision
// table, per-document LDS histogram, coalesced output write.
//
// Shapes (fixed by the reference harness):
//   documents       [N, W, 4] int32   N = 1,048,576, W = 4
//   doc_ids         [N]       int32   SORTED -> each doc is a contiguous range
//   batch_size      scalar    (512)
//   hash_table      [V, C, W] int32   V = 32000, C = 2
//   feature_indices [V, C]    int32
//   powers_of_two   [4]       int32
//   scale           [1]       float32
//   out             [BATCH, V] float32
//
// R2 post-mortem: zero-pass + global atomics structure was ~34.5 us regardless
// of fill speed. New structure: one block per doc, uint16-packed LDS histogram
// (64000 B), single coalesced output write. No pre-zero, no global atomics.

constexpr int V_VOCAB  = 32000;   // compile-time so % becomes magic-mul
constexpr int V_HALF   = V_VOCAB / 2;
constexpr int W_GROUPS = 4;

// Build CSR offsets for sorted doc_ids: offsets[d] = first word index of doc d,
// offsets[B] = N. Handles empty docs.
__global__ __launch_bounds__(256)
void cv_offsets_kernel(const int* __restrict__ doc_ids, int* __restrict__ offsets,
                       int N, int B)
{
    int i = blockIdx.x * blockDim.x + threadIdx.x;
    if (i >= N) return;
    int cur  = doc_ids[i];
    int prev = (i == 0) ? -1 : doc_ids[i - 1];
    for (int d = prev + 1; d <= cur; ++d) offsets[d] = i;
    if (i == N - 1)
        for (int d = cur + 1; d <= B; ++d) offsets[d] = N;
}

__global__ __launch_bounds__(256)
void cv_doc_kernel(const int4* __restrict__ docs,       // [N, W] int4 (4 bytes/group)
                   const int*  __restrict__ offsets,    // [B+1]
                   const int*  __restrict__ hash_table, // [V, C, W]
                   const int2* __restrict__ feat_idx,   // [V] int2 (C=2)
                   const int*  __restrict__ powers,     // [4]
                   const float* __restrict__ scale_p,   // [1]
                   float2* __restrict__ out)            // [BATCH, V] as [BATCH, V/2] float2
{
    // Packed per-doc histogram: bin f lives in half (f&1) of word f>>1.
    // Max count per doc (~2100) << 65536, so no carry between halves.
    __shared__ unsigned cnt[V_HALF];   // 64000 B

    const int b   = blockIdx.x;
    const int tid = threadIdx.x;
    const int start = offsets[b];
    const int end   = offsets[b + 1];

    for (int i = tid; i < V_HALF; i += 256) cnt[i] = 0;

    const int p0 = powers[0], p1 = powers[1], p2 = powers[2], p3 = powers[3];
    const float scale = scale_p[0];
    const unsigned K = 3432918353u * 461845907u;  // c1*c2 mod 2^32, constant-folded

    __syncthreads();

    for (int w = start + tid; w < end; w += 256) {
        int packed[W_GROUPS];
#pragma unroll
        for (int g = 0; g < W_GROUPS; ++g) {
            int4 v = docs[(size_t)w * W_GROUPS + g];
            packed[g] = v.x * p0 + v.y * p1 + v.z * p2 + v.w * p3;
        }

        unsigned h = 0;
#pragma unroll
        for (int g = 0; g < W_GROUPS; ++g) h ^= (unsigned)packed[g] * K;
        unsigned idx = h % (unsigned)V_VOCAB;

        const int4* ht = (const int4*)(hash_table + (size_t)idx * (2 * W_GROUPS));
        int4 e0 = ht[0];
        int4 e1 = ht[1];
        int2 fi = feat_idx[idx];

        bool m0 = (e0.x == packed[0]) & (e0.y == packed[1]) &
                  (e0.z == packed[2]) & (e0.w == packed[3]);
        bool m1 = (e1.x == packed[0]) & (e1.y == packed[1]) &
                  (e1.z == packed[2]) & (e1.w == packed[3]);
        int feat = (m0 ? fi.x : 0) + (m1 ? fi.y : 0);   // 0 = miss

        if (feat > 0) {
            unsigned f = (unsigned)(feat - 1);
            atomicAdd(&cnt[f >> 1], 1u << ((f & 1u) * 16u));
        }
    }

    __syncthreads();

    float2* outd = out + (size_t)b * V_HALF;
    for (int i = tid; i < V_HALF; i += 256) {
        unsigned pr = cnt[i];
        outd[i] = make_float2((float)(pr & 0xFFFFu) * scale,
                              (float)(pr >> 16) * scale);
    }
}

extern "C" void kernel_launch(void* const* d_in, const int* in_sizes, int n_in,
                              void* d_out, int out_size, void* d_ws, size_t ws_size,
                              hipStream_t stream) {
    const int4* docs       = (const int4*)d_in[0];
    const int*  doc_ids    = (const int*) d_in[1];
    // d_in[2] = batch_size scalar (host-side: out_size / V gives BATCH)
    const int*  hash_table = (const int*) d_in[3];
    const int2* feat_idx   = (const int2*)d_in[4];
    const int*  powers     = (const int*) d_in[5];
    const float* scale     = (const float*)d_in[6];
    float2* out = (float2*)d_out;

    const int N = in_sizes[1];            // one doc_id per word
    const int B = out_size / V_VOCAB;     // 512

    int* offsets = (int*)d_ws;            // (B+1) ints of scratch

    cv_offsets_kernel<<<(N + 255) / 256, 256, 0, stream>>>(doc_ids, offsets, N, B);
    cv_doc_kernel<<<B, 256, 0, stream>>>(docs, offsets, hash_table, feat_idx,
                                         powers, scale, out);
}

// Round 4
// 36.282 us; speedup vs baseline: 1.0113x; 1.0113x over previous
//
#include <hip/hip_runtime.h>

// CountVectorizer: hash 4x4-byte packed word groups, look up in collision
// table, per-document LDS histogram, coalesced output write.
//
// Shapes (fixed by the reference harness):
//   documents       [N, W, 4] int32   N = 1,048,576, W = 4
//   doc_ids         [N]       int32   SORTED -> each doc is a contiguous range
//   batch_size      scalar    (512)
//   hash_table      [V, C, W] int32   V = 32000, C = 2
//   feature_indices [V, C]    int32
//   powers_of_two   [4]       int32
//   scale           [1]       float32
//   out             [BATCH, V] float32
//
// R3 post-mortem: 256-thr blocks + 64000B LDS -> 2 blocks/CU = 4 waves/CU
// (12.5% occupancy, measured 13) -> latency-bound at 2.5 TB/s. Fix: 1024-thr
// blocks, __launch_bounds__(1024,8) caps VGPR<=64 so 2 blocks/CU = 32 waves/CU.

constexpr int V_VOCAB  = 32000;   // compile-time so % becomes magic-mul
constexpr int V_HALF   = V_VOCAB / 2;
constexpr int W_GROUPS = 4;
constexpr int BLOCK    = 1024;

// Build CSR offsets for sorted doc_ids: offsets[d] = first word index of doc d,
// offsets[B] = N. Handles empty docs.
__global__ __launch_bounds__(256)
void cv_offsets_kernel(const int* __restrict__ doc_ids, int* __restrict__ offsets,
                       int N, int B)
{
    int i = blockIdx.x * blockDim.x + threadIdx.x;
    if (i >= N) return;
    int cur  = doc_ids[i];
    int prev = (i == 0) ? -1 : doc_ids[i - 1];
    for (int d = prev + 1; d <= cur; ++d) offsets[d] = i;
    if (i == N - 1)
        for (int d = cur + 1; d <= B; ++d) offsets[d] = N;
}

__global__ __launch_bounds__(BLOCK, 8)
void cv_doc_kernel(const int4* __restrict__ docs,       // [N, W] int4 (4 bytes/group)
                   const int*  __restrict__ offsets,    // [B+1]
                   const int*  __restrict__ hash_table, // [V, C, W]
                   const int2* __restrict__ feat_idx,   // [V] int2 (C=2)
                   const int*  __restrict__ powers,     // [4]
                   const float* __restrict__ scale_p,   // [1]
                   float2* __restrict__ out)            // [BATCH, V] as [BATCH, V/2] float2
{
    // Packed per-doc histogram: bin f lives in half (f&1) of word f>>1.
    // Max count per doc (~2100) << 65536, so no carry between halves.
    __shared__ unsigned cnt[V_HALF];   // 64000 B -> 2 blocks/CU

    const int b   = blockIdx.x;
    const int tid = threadIdx.x;
    const int start = offsets[b];
    const int end   = offsets[b + 1];

    for (int i = tid; i < V_HALF; i += BLOCK) cnt[i] = 0;

    const int p0 = powers[0], p1 = powers[1], p2 = powers[2], p3 = powers[3];
    const float scale = scale_p[0];
    const unsigned K = 3432918353u * 461845907u;  // c1*c2 mod 2^32, constant-folded

    __syncthreads();

    for (int w = start + tid; w < end; w += BLOCK) {
        int packed[W_GROUPS];
#pragma unroll
        for (int g = 0; g < W_GROUPS; ++g) {
            int4 v = docs[(size_t)w * W_GROUPS + g];
            packed[g] = v.x * p0 + v.y * p1 + v.z * p2 + v.w * p3;
        }

        unsigned h = 0;
#pragma unroll
        for (int g = 0; g < W_GROUPS; ++g) h ^= (unsigned)packed[g] * K;
        unsigned idx = h % (unsigned)V_VOCAB;

        const int4* ht = (const int4*)(hash_table + (size_t)idx * (2 * W_GROUPS));
        int4 e0 = ht[0];
        int4 e1 = ht[1];
        int2 fi = feat_idx[idx];

        bool m0 = (e0.x == packed[0]) & (e0.y == packed[1]) &
                  (e0.z == packed[2]) & (e0.w == packed[3]);
        bool m1 = (e1.x == packed[0]) & (e1.y == packed[1]) &
                  (e1.z == packed[2]) & (e1.w == packed[3]);
        int feat = (m0 ? fi.x : 0) + (m1 ? fi.y : 0);   // 0 = miss

        if (feat > 0) {
            unsigned f = (unsigned)(feat - 1);
            atomicAdd(&cnt[f >> 1], 1u << ((f & 1u) * 16u));
        }
    }

    __syncthreads();

    float2* outd = out + (size_t)b * V_HALF;
    for (int i = tid; i < V_HALF; i += BLOCK) {
        unsigned pr = cnt[i];
        outd[i] = make_float2((float)(pr & 0xFFFFu) * scale,
                              (float)(pr >> 16) * scale);
    }
}

extern "C" void kernel_launch(void* const* d_in, const int* in_sizes, int n_in,
                              void* d_out, int out_size, void* d_ws, size_t ws_size,
                              hipStream_t stream) {
    const int4* docs       = (const int4*)d_in[0];
    const int*  doc_ids    = (const int*) d_in[1];
    // d_in[2] = batch_size scalar (host-side: out_size / V gives BATCH)
    const int*  hash_table = (const int*) d_in[3];
    const int2* feat_idx   = (const int2*)d_in[4];
    const int*  powers     = (const int*) d_in[5];
    const float* scale     = (const float*)d_in[6];
    float2* out = (float2*)d_out;

    const int N = in_sizes[1];            // one doc_id per word
    const int B = out_size / V_VOCAB;     // 512

    int* offsets = (int*)d_ws;            // (B+1) ints of scratch

    cv_offsets_kernel<<<(N + 255) / 256, 256, 0, stream>>>(doc_ids, offsets, N, B);
    cv_doc_kernel<<<B, BLOCK, 0, stream>>>(docs, offsets, hash_table, feat_idx,
                                           powers, scale, out);
}

// Round 6
// 33.831 us; speedup vs baseline: 1.0846x; 1.0724x over previous
//
#include <hip/hip_runtime.h>

// CountVectorizer: hash 4x4-byte packed word groups, look up in collision
// table, per-document LDS histogram, coalesced output write.
//
// Shapes (fixed by the reference harness):
//   documents       [N, W, 4] int32   N = 1,048,576, W = 4
//   doc_ids         [N]       int32   SORTED -> each doc is a contiguous range
//   batch_size      scalar    (512)
//   hash_table      [V, C, W] int32   V = 32000, C = 2  (slot 1 is all-zero)
//   feature_indices [V, C]    int32
//   powers_of_two   [4]       int32
//   scale           [1]       float32
//   out             [BATCH, V] float32
//
// R4 post-mortem: occupancy 13->50% changed NOTHING (41.4us both) -> read
// phase is not TLP-bound. This version: (1) wave-cooperative loads -- each
// 4-lane group owns one word, so every load instruction covers a contiguous
// 1KB (full 64B lines) instead of 64 scattered 16B granules; hash/match/feat
// combined with __shfl_xor. (2) nontemporal output stores so the 64MB output
// doesn't evict docs from L3 between replays.
// R5: __builtin_nontemporal_store needs a native vector type, not HIP float2
// (class) -- bit-cast through ext_vector_type(2) float.

constexpr int V_VOCAB  = 32000;   // compile-time so % becomes magic-mul
constexpr int V_HALF   = V_VOCAB / 2;
constexpr int BLOCK    = 1024;
constexpr int WAVES    = BLOCK / 64;          // 16
constexpr int CHUNK    = 16;                  // words per wave per chunk
constexpr int STEP     = WAVES * CHUNK;       // 256 words per block-step

typedef float f32x2 __attribute__((ext_vector_type(2)));

// Build CSR offsets for sorted doc_ids: offsets[d] = first word index of doc d,
// offsets[B] = N. Handles empty docs.
__global__ __launch_bounds__(256)
void cv_offsets_kernel(const int* __restrict__ doc_ids, int* __restrict__ offsets,
                       int N, int B)
{
    int i = blockIdx.x * blockDim.x + threadIdx.x;
    if (i >= N) return;
    int cur  = doc_ids[i];
    int prev = (i == 0) ? -1 : doc_ids[i - 1];
    for (int d = prev + 1; d <= cur; ++d) offsets[d] = i;
    if (i == N - 1)
        for (int d = cur + 1; d <= B; ++d) offsets[d] = N;
}

__global__ __launch_bounds__(BLOCK, 8)
void cv_doc_kernel(const int4* __restrict__ docs,       // [N*4] int4, word w = [w*4 .. w*4+3]
                   const int*  __restrict__ offsets,    // [B+1]
                   const int*  __restrict__ hash_table, // [V, 2, 4]
                   const int*  __restrict__ feat_idx,   // [V, 2]
                   const int*  __restrict__ powers,     // [4]
                   const float* __restrict__ scale_p,   // [1]
                   f32x2* __restrict__ out)             // [BATCH, V/2] float pairs
{
    // Packed per-doc histogram: bin f lives in half (f&1) of word f>>1.
    // Max count per doc (~2100) << 65536, so no carry between halves.
    __shared__ unsigned cnt[V_HALF];   // 64000 B -> 2 blocks/CU

    const int b    = blockIdx.x;
    const int tid  = threadIdx.x;
    const int lane = tid & 63;
    const int wave = tid >> 6;
    const int g    = lane & 3;        // byte-group owned by this lane
    const int q    = lane >> 2;       // word-within-chunk (0..15)

    const int start = offsets[b];
    const int end   = offsets[b + 1];

    for (int i = tid; i < V_HALF; i += BLOCK) cnt[i] = 0;

    const int p0 = powers[0], p1 = powers[1], p2 = powers[2], p3 = powers[3];
    const float scale = scale_p[0];
    const unsigned K = 3432918353u * 461845907u;  // c1*c2 mod 2^32, constant-folded

    __syncthreads();

    // Per chunk: 4-lane group handles word w; lane g loads group g (16B).
    // A wave's 64 lanes cover 16 consecutive words = contiguous 1KB.
#define CHUNK_BODY(W_IDX)                                                      \
    {                                                                          \
        const int w = (W_IDX);                                                 \
        const bool valid = (w < end);                                          \
        int4 v = valid ? docs[(size_t)w * 4 + g] : make_int4(0, 0, 0, 0);      \
        int packed = v.x * p0 + v.y * p1 + v.z * p2 + v.w * p3;                \
        unsigned bq = (unsigned)packed * K;                                    \
        unsigned h = bq ^ (unsigned)__shfl_xor((int)bq, 1, 64);                \
        h ^= (unsigned)__shfl_xor((int)h, 2, 64);                              \
        unsigned idx = h % (unsigned)V_VOCAB;                                  \
        int ew0 = hash_table[idx * 8 + g];       /* slot0, group g */          \
        int ew1 = hash_table[idx * 8 + 4 + g];   /* slot1, group g */          \
        int fiv = feat_idx[idx * 2 + (g & 1)];   /* fi.x / fi.y */             \
        unsigned t = (ew0 == packed ? 1u : 0u) | (ew1 == packed ? 2u : 0u);    \
        t &= (unsigned)__shfl_xor((int)t, 1, 64);                              \
        t &= (unsigned)__shfl_xor((int)t, 2, 64);                              \
        int cand = (g < 2 && ((t >> g) & 1u)) ? fiv : 0;                       \
        cand += __shfl_xor(cand, 1, 64);                                       \
        cand += __shfl_xor(cand, 2, 64);                                       \
        if (g == 0 && valid && cand > 0) {                                     \
            unsigned f = (unsigned)(cand - 1);                                 \
            atomicAdd(&cnt[f >> 1], 1u << ((f & 1u) * 16u));                   \
        }                                                                      \
    }

    // Dual-chunk body: two independent chunks in flight per iteration.
    for (int base = start; base < end; base += 2 * STEP) {
        int wA = base + wave * CHUNK + q;
        CHUNK_BODY(wA)
        CHUNK_BODY(wA + STEP)
    }
#undef CHUNK_BODY

    __syncthreads();

    f32x2* outd = out + (size_t)b * V_HALF;
    for (int i = tid; i < V_HALF; i += BLOCK) {
        unsigned pr = cnt[i];
        f32x2 val;
        val.x = (float)(pr & 0xFFFFu) * scale;
        val.y = (float)(pr >> 16) * scale;
        __builtin_nontemporal_store(val, &outd[i]);
    }
}

extern "C" void kernel_launch(void* const* d_in, const int* in_sizes, int n_in,
                              void* d_out, int out_size, void* d_ws, size_t ws_size,
                              hipStream_t stream) {
    const int4* docs       = (const int4*)d_in[0];
    const int*  doc_ids    = (const int*) d_in[1];
    // d_in[2] = batch_size scalar (host-side: out_size / V gives BATCH)
    const int*  hash_table = (const int*) d_in[3];
    const int*  feat_idx   = (const int*) d_in[4];
    const int*  powers     = (const int*) d_in[5];
    const float* scale     = (const float*)d_in[6];
    f32x2* out = (f32x2*)d_out;

    const int N = in_sizes[1];            // one doc_id per word
    const int B = out_size / V_VOCAB;     // 512

    int* offsets = (int*)d_ws;            // (B+1) ints of scratch

    cv_offsets_kernel<<<(N + 255) / 256, 256, 0, stream>>>(doc_ids, offsets, N, B);
    cv_doc_kernel<<<B, BLOCK, 0, stream>>>(docs, offsets, hash_table, feat_idx,
                                           powers, scale, out);
}